// Round 10
// baseline (62.001 us; speedup 1.0000x reference)
//
#include <hip/hip_runtime.h>

#define LL    4096
#define OUTL  8191
#define FPAD  272
#define NPDW  2336          // dwords per fwd copy: elements -272..4399 (need <=4367)
#define CB1   2352          // copy1 base (16-dw stagger)
#define RB    4688          // rev-copy base dword (4-dw aligned)
#define BTOP  5887          // rev top x-index (== 7 mod 8)
#define LDSDW 8656          // 34.6 KB -> 4 blocks/CU

typedef short v8s __attribute__((ext_vector_type(8)));
typedef float v4f __attribute__((ext_vector_type(4)));

__device__ __forceinline__ unsigned bf16b(float f) {
    unsigned u = __builtin_bit_cast(unsigned, f);
    u += 0x7fff + ((u >> 16) & 1);          // RNE
    return u >> 16;
}
__device__ __forceinline__ unsigned pk(float lo, float hi) {
    return bf16b(lo) | (bf16b(hi) << 16);
}
// 16B-unit swizzle: bank-quad = (g mod 16)>>1 -> stride-(-2) b128 lane phases
// hit 8 distinct quads. Linear under all strides used (multiples of 16 units).
__device__ __forceinline__ int swz(int g) {
    return (g & ~15) | ((g & 1) << 3) | ((g & 15) >> 1);
}

__global__ __launch_bounds__(512, 8)
void selfconv_mfma8(const float* __restrict__ xg, float* __restrict__ outg) {
    __shared__ unsigned lds[LDSDW];
    const int tid = threadIdx.x;
    const int blk = blockIdx.x;
    const int b   = blk & 127;
    const int id  = blk >> 7;
    // per-CU balance: co-resident region sets sum to equal chunk counts
    const int perm[8] = {0, 3, 1, 2, 5, 6, 4, 7};
    const int rg  = perm[id];
    const int T0  = rg << 10;                       // 1024-output region
    const float* __restrict__ xb = xg + b * LL;

    // ---- fwd staging: 2 parity copies; thread w covers elements E..E+8 ----
#pragma unroll
    for (int rr = 0; rr < 2; ++rr) {
        int w = tid + rr * 512;
        if (w < 584) {
            int E = 8 * w - FPAD;
            float e0,e1,e2,e3,e4,e5,e6,e7,e8;
            if (E >= 0 && E + 8 < LL) {
                float4 fa = *(const float4*)(xb + E);
                float4 fb = *(const float4*)(xb + E + 4);
                e0=fa.x; e1=fa.y; e2=fa.z; e3=fa.w;
                e4=fb.x; e5=fb.y; e6=fb.z; e7=fb.w; e8=xb[E+8];
            } else {
                float t[9];
#pragma unroll
                for (int k = 0; k < 9; ++k) {
                    int e = E + k;
                    t[k] = (e >= 0 && e < LL) ? xb[e] : 0.f;
                }
                e0=t[0]; e1=t[1]; e2=t[2]; e3=t[3]; e4=t[4];
                e5=t[5]; e6=t[6]; e7=t[7]; e8=t[8];
            }
            uint4 d0{pk(e0,e1), pk(e2,e3), pk(e4,e5), pk(e6,e7)};
            uint4 d1{pk(e1,e2), pk(e3,e4), pk(e5,e6), pk(e7,e8)};
            *(uint4*)&lds[4 * w]       = d0;
            *(uint4*)&lds[CB1 + 4 * w] = d1;
        }
    }
    // ---- rev staging: unit g = yr[8g..8g+7] = x[BTOP-8g-7..BTOP-8g] ----
    {
        int g = 224 + tid;                          // exactly 512 in-range units
        int x0 = BTOP - 7 - 8 * g;
        float4 fa = *(const float4*)(xb + x0);
        float4 fb = *(const float4*)(xb + x0 + 4);
        uint4 o{pk(fb.w, fb.z), pk(fb.y, fb.x), pk(fa.w, fa.z), pk(fa.y, fa.x)};
        *(uint4*)&lds[RB + 4 * swz(g)] = o;
    }
    if (tid < 480) {                                // zero pads (16-block closed)
        int u = (tid < 224) ? tid : tid + 512;
        *(uint4*)&lds[RB + 4 * u] = uint4{0, 0, 0, 0};
    }
    __syncthreads();

    const int wv = tid >> 6, lane = tid & 63, ln16 = lane & 15, q = lane >> 4;

    // i-union over 4 tiles: base = T0 + 256u + 512v, u,v in {0,1}
    int mn = 0x7fffffff, mx = -0x7fffffff;
#pragma unroll
    for (int u = 0; u < 2; ++u)
#pragma unroll
        for (int v = 0; v < 2; ++v) {
            int base = T0 + 256 * u + 512 * v;
            int iLo = base - (LL - 1); if (iLo < 0) iLo = 0;
            int iHi = base + 255;      if (iHi > LL - 1) iHi = LL - 1;
            int a = iLo - 256 * u; if (a < mn) mn = a;
            int c2 = iHi - 256 * u; if (c2 > mx) mx = c2;
        }
    const int base_   = mn - 15;
    const int i0start = base_ - ((base_ - 1) & 7);   // == 1 mod 8
    const int nch     = ((mx - i0start) >> 5) + 1;
    const int nw      = (nch - wv + 7) >> 3;         // 8-way i-split (exact)
    const int i0w     = i0start + 32 * wv;

    // A: x[i0 + m + 8q + j]; parity picks fwd copy; +128 dw = u=1 tile
    const int s0p = i0w + ln16 + 8 * q + FPAD;
    int aw = (s0p >> 1) + ((s0p & 1) ? CB1 : 0);
    // B(v=1): yr at e' = BTOP - T0 - 512 - 16n + i0 + 8q  (==0 mod 8)
    const int g1 = (BTOP - T0 - 512 - 16 * ln16 + i0w + 8 * q) >> 3;
    int bw = RB + 4 * swz(g1);
    // per wave-chunk: i0 += 256 -> aw += 128 dw, bw += 128 dw (32 units, linear)

    v4f a00{0,0,0,0}, a10{0,0,0,0}, a01{0,0,0,0}, a11{0,0,0,0};

    auto mkA = [](unsigned u0, unsigned u1, unsigned u2, unsigned u3) {
        union { unsigned x[4]; v8s s; } z;
        z.x[0] = u0; z.x[1] = u1; z.x[2] = u2; z.x[3] = u3; return z.s;
    };
    auto mkB = [](uint4 v) {
        union { unsigned x[4]; v8s s; } z;
        z.x[0] = v.x; z.x[1] = v.y; z.x[2] = v.z; z.x[3] = v.w; return z.s;
    };

    for (int c = 0; c < nw; ++c) {
        unsigned x0 = lds[aw],       x1 = lds[aw + 1];
        unsigned x2 = lds[aw + 2],   x3 = lds[aw + 3];
        unsigned y0 = lds[aw + 128], y1 = lds[aw + 129];
        unsigned y2 = lds[aw + 130], y3 = lds[aw + 131];
        uint4 bv1 = *(const uint4*)&lds[bw];         // v=1 tile
        uint4 bv0 = *(const uint4*)&lds[bw + 256];   // v=0 tile (+64 units)
        v8s A0 = mkA(x0, x1, x2, x3);
        v8s A1 = mkA(y0, y1, y2, y3);
        v8s B1 = mkB(bv1);
        v8s B0 = mkB(bv0);
        a00 = __builtin_amdgcn_mfma_f32_16x16x32_bf16(A0, B0, a00, 0, 0, 0);
        a10 = __builtin_amdgcn_mfma_f32_16x16x32_bf16(A1, B0, a10, 0, 0, 0);
        a01 = __builtin_amdgcn_mfma_f32_16x16x32_bf16(A0, B1, a01, 0, 0, 0);
        a11 = __builtin_amdgcn_mfma_f32_16x16x32_bf16(A1, B1, a11, 0, 0, 0);
        aw += 128; bw += 128;
    }

    // ---- 8->1 reduction tree over scratch (stride 20 dw) ----
    float* fs = (float*)lds;
    auto dump = [&](int slot) {
        int sb = slot * 1280 + lane * 20;
        *(v4f*)&fs[sb]      = a00; *(v4f*)&fs[sb + 4]  = a10;
        *(v4f*)&fs[sb + 8]  = a01; *(v4f*)&fs[sb + 12] = a11;
    };
    auto gather = [&](int slot) {
        int sb = slot * 1280 + lane * 20;
        a00 += *(const v4f*)&fs[sb];      a10 += *(const v4f*)&fs[sb + 4];
        a01 += *(const v4f*)&fs[sb + 8];  a11 += *(const v4f*)&fs[sb + 12];
    };
    __syncthreads();
    if (wv >= 4) dump(wv - 4);
    __syncthreads();
    if (wv < 4) gather(wv);
    __syncthreads();
    if (wv == 2 || wv == 3) dump(wv - 2);
    __syncthreads();
    if (wv < 2) gather(wv);
    __syncthreads();
    if (wv == 1) dump(0);
    __syncthreads();
    if (wv == 0) {
        gather(0);
        float* __restrict__ ob = outg + b * OUTL;
        const v4f* accs[4] = {&a00, &a10, &a01, &a11};
        const int offs[4]  = {0, 256, 512, 768};
#pragma unroll
        for (int t4 = 0; t4 < 4; ++t4) {
            int tilebase = T0 + offs[t4];
            int tb = tilebase + 4 * q + 16 * ln16;
            v4f a = *accs[t4];
            if (tilebase + 255 < OUTL) {
                *(v4f*)&ob[tb] = a;
            } else {
#pragma unroll
                for (int r2 = 0; r2 < 4; ++r2)
                    if (tb + r2 < OUTL) ob[tb + r2] = a[r2];
            }
        }
    }
}

extern "C" void kernel_launch(void* const* d_in, const int* in_sizes, int n_in,
                              void* d_out, int out_size, void* d_ws, size_t ws_size,
                              hipStream_t stream) {
    const float* x = (const float*)d_in[0];
    float* out = (float*)d_out;
    selfconv_mfma8<<<dim3(1024), dim3(512), 0, stream>>>(x, out);
}